// Round 5
// baseline (161.128 us; speedup 1.0000x reference)
//
#include <hip/hip_runtime.h>

// ---- problem constants (from reference) ----
constexpr int T_LEN    = 192000;            // samples per signal
constexpr int N_SIG    = 512;               // 16*32 signals per input
constexpr int FRAME    = 9600;              // 0.4 s @ 24 kHz
constexpr int SHIFT    = 2880;              // 70% overlap
constexpr int SUB      = 960;               // gcd(FRAME, SHIFT)
constexpr int NFRAMES  = (T_LEN - FRAME) / SHIFT + 1;   // 64
constexpr int SUB_PER_SHIFT = SHIFT / SUB;  // 3
constexpr int SUB_PER_FRAME = FRAME / SUB;  // 10
constexpr int NSUB     = (NFRAMES - 1) * SUB_PER_SHIFT + SUB_PER_FRAME; // 199
constexpr int F4_PER_SUB = SUB / 4;         // 240 float4 per sub-block

typedef float f32x4 __attribute__((ext_vector_type(4)));

__device__ __forceinline__ float wave_reduce_f32(float v) {
    #pragma unroll
    for (int off = 32; off > 0; off >>= 1) v += __shfl_xor(v, off);
    return v;
}

__device__ __forceinline__ double wave_reduce_f64(double v) {
    #pragma unroll
    for (int off = 32; off > 0; off >>= 1) v += __shfl_xor(v, off);
    return v;
}

// One block per (input p, signal n): EXACT round-3 streaming structure
// (1024 blocks x 4 waves, nontemporal float4 loads, per-sub-block wave
// reduce -> LDS, wave-0 f64 gating epilogue). The only addition: lufs is
// stored to d_ws, and the LAST block (agent-scope ticket) does the
// fixed-order hinge reduction in-kernel, replacing the second dispatch.
__global__ __launch_bounds__(256) void dhaspi_loudness_kernel(
    const float* __restrict__ x, const float* __restrict__ y,
    double* __restrict__ lufs_ws,          // [1024]: [x lufs | y lufs]
    unsigned int* __restrict__ cnt,        // [1], zeroed per call (memset node)
    float* __restrict__ out)
{
    const int bid  = blockIdx.x;
    const int p    = bid >> 9;            // 0 = x, 1 = y
    const int n    = bid & (N_SIG - 1);
    const float* sig = (p == 0 ? x : y) + (size_t)n * T_LEN;
    const f32x4* sig4 = reinterpret_cast<const f32x4*>(sig);

    __shared__ float s_sub[NSUB];
    __shared__ bool  s_win;

    const int tid  = threadIdx.x;
    const int wave = tid >> 6;
    const int lane = tid & 63;

    for (int k = wave; k < NSUB; k += 4) {
        float acc = 0.0f;
        const int base = k * F4_PER_SUB;
        #pragma unroll
        for (int i = 0; i < 4; ++i) {
            int idx = i * 64 + lane;
            if (idx < F4_PER_SUB) {
                f32x4 v = __builtin_nontemporal_load(&sig4[base + idx]);
                acc += v.x * v.x + v.y * v.y + v.z * v.z + v.w * v.w;
            }
        }
        acc = wave_reduce_f32(acc);
        if (lane == 0) s_sub[k] = acc;
    }
    __syncthreads();

    if (wave == 0) {
        // one frame per lane (NFRAMES == 64 exactly)
        float zs = 0.0f;
        const int b0 = lane * SUB_PER_SHIFT;
        #pragma unroll
        for (int j = 0; j < SUB_PER_FRAME; ++j) zs += s_sub[b0 + j];
        const double z  = (double)zs / (double)FRAME;   // mean-square energy
        const double el = -0.691 + 10.0 * log10(z + 1e-8);

        // absolute gating
        const double ia = (el > -70.0) ? 1.0 : 0.0;
        double sz = wave_reduce_f64(z * ia);
        double si = wave_reduce_f64(ia);
        const double z_ave_a = sz / (si + 1e-8);

        // relative gating: 10 dB below absolute-gated loudness
        const double gamma_r = -0.691 + 10.0 * log10(z_ave_a + 1e-8) - 10.0;
        const double iar = ia * ((el > gamma_r) ? 1.0 : 0.0);
        double sz2 = wave_reduce_f64(z * iar);
        double si2 = wave_reduce_f64(iar);
        const double z_ave_ar = sz2 / (si2 + 1e-8);

        const double lufs = -0.691 + 10.0 * log10(z_ave_ar + 1e-8);
        if (lane == 0) {
            // agent-scope store so the winner (any XCD) sees it
            __hip_atomic_store(&lufs_ws[bid], lufs, __ATOMIC_RELAXED,
                               __HIP_MEMORY_SCOPE_AGENT);
        }
    }
    __syncthreads();

    if (tid == 0) {
        // acq_rel ticket: releases our lufs store, acquires everyone else's
        unsigned int old = __hip_atomic_fetch_add(cnt, 1u, __ATOMIC_ACQ_REL,
                                                  __HIP_MEMORY_SCOPE_AGENT);
        s_win = (old == (unsigned int)(gridDim.x - 1));
    }
    __syncthreads();

    if (s_win) {
        // fixed-order hinge reduction over 512 pairs: bit-exact every replay
        const double lx0 = __hip_atomic_load(&lufs_ws[tid], __ATOMIC_RELAXED,
                                             __HIP_MEMORY_SCOPE_AGENT);
        const double ly0 = __hip_atomic_load(&lufs_ws[N_SIG + tid], __ATOMIC_RELAXED,
                                             __HIP_MEMORY_SCOPE_AGENT);
        const double lx1 = __hip_atomic_load(&lufs_ws[256 + tid], __ATOMIC_RELAXED,
                                             __HIP_MEMORY_SCOPE_AGENT);
        const double ly1 = __hip_atomic_load(&lufs_ws[N_SIG + 256 + tid], __ATOMIC_RELAXED,
                                             __HIP_MEMORY_SCOPE_AGENT);
        const double h0 = (ly0 - lx0 > 0.0) ? (ly0 - lx0) : 0.0;
        const double h1 = (ly1 - lx1 > 0.0) ? (ly1 - lx1) : 0.0;
        double v = wave_reduce_f64(h0 + h1);

        __shared__ double sd[4];
        if (lane == 0) sd[wave] = v;
        __syncthreads();
        if (tid == 0) {
            double t = 0.0;
            #pragma unroll
            for (int i = 0; i < 4; ++i) t += sd[i];
            out[0] = (float)(1e-4 * t);
        }
    }
}

extern "C" void kernel_launch(void* const* d_in, const int* in_sizes, int n_in,
                              void* d_out, int out_size, void* d_ws, size_t ws_size,
                              hipStream_t stream) {
    const float* x = (const float*)d_in[0];
    const float* y = (const float*)d_in[1];
    float* out = (float*)d_out;

    // d_ws layout: [0, 8192) lufs doubles (rewritten fully every call),
    //              [8192, 8196) ticket counter (zeroed per call below)
    double* lufs_ws = (double*)d_ws;
    unsigned int* cnt = (unsigned int*)((char*)d_ws + 2 * N_SIG * sizeof(double));

    hipMemsetAsync(cnt, 0, sizeof(unsigned int), stream);
    dhaspi_loudness_kernel<<<2 * N_SIG, 256, 0, stream>>>(x, y, lufs_ws, cnt, out);
}

// Round 6
// 120.151 us; speedup vs baseline: 1.3410x; 1.3410x over previous
//
#include <hip/hip_runtime.h>

// ---- problem constants (from reference) ----
constexpr int T_LEN    = 192000;            // samples per signal
constexpr int N_SIG    = 512;               // 16*32 signals per input
constexpr int FRAME    = 9600;              // 0.4 s @ 24 kHz
constexpr int SHIFT    = 2880;              // 70% overlap
constexpr int SUB      = 960;               // gcd(FRAME, SHIFT)
constexpr int NFRAMES  = (T_LEN - FRAME) / SHIFT + 1;   // 64
constexpr int SUB_PER_SHIFT = SHIFT / SUB;  // 3
constexpr int SUB_PER_FRAME = FRAME / SUB;  // 10
constexpr int NSUB     = (NFRAMES - 1) * SUB_PER_SHIFT + SUB_PER_FRAME; // 199
constexpr int F4_PER_SUB = SUB / 4;         // 240 float4 per sub-block

typedef float f32x4 __attribute__((ext_vector_type(4)));

__device__ __forceinline__ float wave_reduce_f32(float v) {
    #pragma unroll
    for (int off = 32; off > 0; off >>= 1) v += __shfl_xor(v, off);
    return v;
}

__device__ __forceinline__ double wave_reduce_f64(double v) {
    #pragma unroll
    for (int off = 32; off > 0; off >>= 1) v += __shfl_xor(v, off);
    return v;
}

// One block per (input p, signal n). 256 threads = 4 waves.
// Wave w handles sub-blocks w, w+4, ...; each sub-block = 240 float4,
// coalesced nontemporal loads, per-lane square-accumulate, wave tree-reduce -> LDS.
// Then wave 0: one frame per lane, gating epilogue in f64.
// (Exact round-3 kernel — best measured: 120.2 us, main kernel ~6.7 TB/s,
//  >=97% of this board's observed streaming ceiling. Fusion variants R4/R5
//  both regressed; two-dispatch structure is the winner.)
__global__ __launch_bounds__(256) void dhaspi_loudness_kernel(
    const float* __restrict__ x, const float* __restrict__ y,
    float* __restrict__ lufs_out)
{
    const int bid  = blockIdx.x;
    const int p    = bid >> 9;            // 0 = x, 1 = y
    const int n    = bid & (N_SIG - 1);
    const float* sig = (p == 0 ? x : y) + (size_t)n * T_LEN;
    const f32x4* sig4 = reinterpret_cast<const f32x4*>(sig);

    __shared__ float s_sub[NSUB];

    const int tid  = threadIdx.x;
    const int wave = tid >> 6;
    const int lane = tid & 63;

    for (int k = wave; k < NSUB; k += 4) {
        float acc = 0.0f;
        const int base = k * F4_PER_SUB;
        #pragma unroll
        for (int i = 0; i < 4; ++i) {
            int idx = i * 64 + lane;
            if (idx < F4_PER_SUB) {
                f32x4 v = __builtin_nontemporal_load(&sig4[base + idx]);
                acc += v.x * v.x + v.y * v.y + v.z * v.z + v.w * v.w;
            }
        }
        acc = wave_reduce_f32(acc);
        if (lane == 0) s_sub[k] = acc;
    }
    __syncthreads();

    if (wave == 0) {
        // one frame per lane (NFRAMES == 64 exactly)
        float zs = 0.0f;
        const int b0 = lane * SUB_PER_SHIFT;
        #pragma unroll
        for (int j = 0; j < SUB_PER_FRAME; ++j) zs += s_sub[b0 + j];
        const double z  = (double)zs / (double)FRAME;   // mean-square energy
        const double el = -0.691 + 10.0 * log10(z + 1e-8);

        // absolute gating
        const double ia = (el > -70.0) ? 1.0 : 0.0;
        double sz = wave_reduce_f64(z * ia);
        double si = wave_reduce_f64(ia);
        const double z_ave_a = sz / (si + 1e-8);

        // relative gating: 10 dB below absolute-gated loudness
        const double gamma_r = -0.691 + 10.0 * log10(z_ave_a + 1e-8) - 10.0;
        const double iar = ia * ((el > gamma_r) ? 1.0 : 0.0);
        double sz2 = wave_reduce_f64(z * iar);
        double si2 = wave_reduce_f64(iar);
        const double z_ave_ar = sz2 / (si2 + 1e-8);

        const double lufs = -0.691 + 10.0 * log10(z_ave_ar + 1e-8);
        if (lane == 0) lufs_out[bid] = (float)lufs;
    }
}

// Final hinge-sum over 512 signals: loss = 1e-4 * sum(max(ly - lx, 0)).
__global__ __launch_bounds__(512) void dhaspi_loss_kernel(
    const float* __restrict__ lufs, float* __restrict__ out)
{
    const int tid  = threadIdx.x;
    const int wave = tid >> 6;
    const int lane = tid & 63;

    const float lx = lufs[tid];
    const float ly = lufs[N_SIG + tid];
    const float d  = ly - lx;
    double v = (d > 0.0f) ? (double)d : 0.0;
    v = wave_reduce_f64(v);

    __shared__ double s[8];
    if (lane == 0) s[wave] = v;
    __syncthreads();
    if (tid == 0) {
        double t = 0.0;
        #pragma unroll
        for (int i = 0; i < 8; ++i) t += s[i];
        out[0] = (float)(1e-4 * t);
    }
}

extern "C" void kernel_launch(void* const* d_in, const int* in_sizes, int n_in,
                              void* d_out, int out_size, void* d_ws, size_t ws_size,
                              hipStream_t stream) {
    const float* x = (const float*)d_in[0];
    const float* y = (const float*)d_in[1];
    float* lufs = (float*)d_ws;          // 1024 floats: [x lufs | y lufs]
    float* out  = (float*)d_out;

    dhaspi_loudness_kernel<<<2 * N_SIG, 256, 0, stream>>>(x, y, lufs);
    dhaspi_loss_kernel<<<1, 512, 0, stream>>>(lufs, out);
}